// Round 1
// 112.283 us; speedup vs baseline: 1.0571x; 1.0571x over previous
//
#include <hip/hip_runtime.h>

// Problem constants (B=2, S=512, D=128, DG=64, NG=2)
#define BQ 2
#define SQ 512
#define DQ 128
#define DGQ 64
#define NGQ 2

typedef float f32x4 __attribute__((ext_vector_type(4)));
typedef __bf16 bf16x8 __attribute__((ext_vector_type(8)));

// ws layout (floats):
//   QW1 : [B*S][128]          @ 0        (= (x@Wq)@blkdiag(W1) + b1, per group)
//   KW1 : [B*S][128]          @ 131072
//   Vp  : [B*S][NG][DG]       @ 262144   (group-major V for coalesced A@V)

// ---------------------------------------------------------------------------
// Kernel 1: fused projections. One block per row (1024 blocks x 256 thr).
// Phase A: Q,K,V rows via split-K over 2 halves (part[] in LDS).
// Phase B: apply W1 per group: QW1 = Q@blkdiag(W1)+b1, KW1 = K@blkdiag(W1).
// Exploits linearity: relu((Q_i-K_j)@W1 + b1) == relu(QW1_i - KW1_j).
// ---------------------------------------------------------------------------
__global__ __launch_bounds__(256) void proj_kernel(
    const float* __restrict__ x,
    const float* __restrict__ Wq, const float* __restrict__ Wk,
    const float* __restrict__ Wv,
    const float* __restrict__ W1, const float* __restrict__ b1,
    float* __restrict__ QW1, float* __restrict__ KW1, float* __restrict__ Vp)
{
    const int t = threadIdx.x;
    const int row = blockIdx.x;            // flat b*S+s, 1024 rows
    __shared__ float xs[DQ];
    __shared__ float part[3][2][DQ];
    __shared__ float qs[DQ], ks[DQ];

    if (t < DQ) xs[t] = x[(size_t)row * DQ + t];
    __syncthreads();

    const int f = t & 127, h = t >> 7;     // feature, K-half
    float aq = 0.f, ak = 0.f, av = 0.f;
    const int d0 = h * 64;
    #pragma unroll 8
    for (int d = 0; d < 64; ++d) {
        const float xv = xs[d0 + d];                       // LDS broadcast
        const size_t o = (size_t)(d0 + d) * DQ + f;        // 256B/wave coalesced
        aq = fmaf(xv, Wq[o], aq);
        ak = fmaf(xv, Wk[o], ak);
        av = fmaf(xv, Wv[o], av);
    }
    part[0][h][f] = aq; part[1][h][f] = ak; part[2][h][f] = av;
    __syncthreads();

    if (t < DQ) {
        qs[t] = part[0][0][t] + part[0][1][t];
        const float v = part[2][0][t] + part[2][1][t];
        // feature f = dg*NG+g  ->  Vp[row][g][dg]
        Vp[((size_t)row * NGQ + (t & 1)) * DGQ + (t >> 1)] = v;
    } else {
        const int f2 = t - DQ;
        ks[f2] = part[1][0][f2] + part[1][1][f2];
    }
    __syncthreads();

    // Phase B: 256 tasks = {q-side, k-side} x 128 features
    const int fb = t & 127, side = t >> 7;
    const int g = fb >> 6, c = fb & 63;
    const float* src = side ? ks : qs;
    float acc = side ? 0.f : b1[c];
    #pragma unroll 8
    for (int e = 0; e < 64; ++e)
        acc = fmaf(src[g * 64 + e], W1[e * DGQ + c], acc);
    (side ? KW1 : QW1)[(size_t)row * DQ + fb] = acc;
}

// ---------------------------------------------------------------------------
// Kernel 2 (MFMA rewrite): one block per (b, g, 4-query tile); 512 threads.
// The per-pair scoring GEMM  relu(QW1_i - KW1_j) @ W2  (1M x 64 x 16 MACs)
// moves to v_mfma_f32_16x16x32_bf16 with a hi/lo split (3 MFMAs per K=32)
// so the result keeps ~fp32 accuracy (bf16 exponent range => no denorm
// hazard in the lo term; residual error ~2^-17 relative).
//
// Fragment k-mapping: k = H*32 + (e>>2)*16 + (lane>>4)*4 + (e&3). Both A and
// B fragments are built with the SAME mapping, so any bijection error in the
// k permutation cancels in sum_k A[j][k]*B[k][ch]. Only HW-verified facts are
// load-bearing: operand row/col = lane&15; C/D col=lane&15, row=(lane>>4)*4+r.
//
// Wave w owns keys [w*64, w*64+64): K rows live in 32 VGPRs per pass
// (2 passes x 2 MFMA row-tiles), reused across the 4 queries.
// ---------------------------------------------------------------------------
__global__ __launch_bounds__(512, 4) void attn_kernel(
    const float* __restrict__ QW1, const float* __restrict__ KW1,
    const float* __restrict__ Vp,
    const float* __restrict__ W2, const float* __restrict__ b2,
    const float* __restrict__ W3, const float* __restrict__ b3,
    const float* __restrict__ pos_add, const float* __restrict__ pos_mul,
    float* __restrict__ out)
{
    const int t = threadIdx.x;
    const int lane = t & 63, w = t >> 6;
    const int lg = lane >> 4, lr = lane & 15;
    const int ib = blockIdx.x & 127;
    const int g  = (blockIdx.x >> 7) & 1;
    const int b  = blockIdx.x >> 8;
    const int i0 = ib * 4;

    __shared__ __align__(16) float Qs[4][DGQ];
    __shared__ __align__(16) float logits[4][SQ];     // raw a (pre b3/bias)
    __shared__ __align__(16) float pbuf[SQ * 4];      // exp'd probs, [j][i]
    __shared__ __align__(16) float avs[8][DGQ][4];    // partial A@V per wave
    __shared__ float redm[4][2], reds[4][2];

    // stage the 4 query rows (group slice)
    if (t < 256) {
        const int i = t >> 6, k = t & 63;
        Qs[i][k] = QW1[((size_t)(b * SQ + i0 + i)) * DQ + g * DGQ + k];
    }

    // per-lane W2 fragments, hi/lo split (built once; k-mapping shared w/ A)
    bf16x8 bhf[2], blf[2];
    #pragma unroll
    for (int H = 0; H < 2; ++H) {
        #pragma unroll
        for (int e = 0; e < 8; ++e) {
            const int k = H * 32 + (e >> 2) * 16 + lg * 4 + (e & 3);
            const float wv = W2[k * 16 + lr];
            const __bf16 hi = (__bf16)wv;
            bhf[H][e] = hi;
            blf[H][e] = (__bf16)(wv - (float)hi);
        }
    }
    const float w3r = W3[lr];
    const float b2r = b2[lr];
    const float b3s = b3[0];

    __syncthreads();

    // ---- main: 2 passes x (4 queries x 2 row-tiles of 16 keys) ----
    #pragma unroll
    for (int pass = 0; pass < 2; ++pass) {
        const int jb0 = w * 64 + pass * 32;
        f32x4 kreg[2][4];
        #pragma unroll
        for (int u = 0; u < 2; ++u) {
            const float* kr =
                KW1 + ((size_t)(b * SQ + jb0 + u * 16 + lr)) * DQ + g * DGQ;
            #pragma unroll
            for (int c = 0; c < 4; ++c)
                kreg[u][c] = *reinterpret_cast<const f32x4*>(
                    kr + (c & 1) * 16 + (c >> 1) * 32 + lg * 4);
        }
        #pragma unroll
        for (int i = 0; i < 4; ++i) {
            f32x4 qf[4];
            #pragma unroll
            for (int c = 0; c < 4; ++c)
                qf[c] = *reinterpret_cast<const f32x4*>(
                    &Qs[i][(c & 1) * 16 + (c >> 1) * 32 + lg * 4]);
            #pragma unroll
            for (int u = 0; u < 2; ++u) {
                f32x4 acc = {0.f, 0.f, 0.f, 0.f};
                #pragma unroll
                for (int H = 0; H < 2; ++H) {
                    bf16x8 ah, al;
                    #pragma unroll
                    for (int cc = 0; cc < 2; ++cc) {
                        const int c = H * 2 + cc;
                        #pragma unroll
                        for (int e = 0; e < 4; ++e) {
                            const float hv =
                                fmaxf(qf[c][e] - kreg[u][c][e], 0.f);
                            const __bf16 hb = (__bf16)hv;
                            ah[cc * 4 + e] = hb;
                            al[cc * 4 + e] = (__bf16)(hv - (float)hb);
                        }
                    }
                    acc = __builtin_amdgcn_mfma_f32_16x16x32_bf16(
                        ah, bhf[H], acc, 0, 0, 0);
                    acc = __builtin_amdgcn_mfma_f32_16x16x32_bf16(
                        al, bhf[H], acc, 0, 0, 0);
                    acc = __builtin_amdgcn_mfma_f32_16x16x32_bf16(
                        ah, blf[H], acc, 0, 0, 0);
                }
                // h2 = relu(acc + b2[ch]); s = h2 * W3[ch]; reduce over 16 ch
                float s0 = fmaxf(acc[0] + b2r, 0.f) * w3r;
                float s1 = fmaxf(acc[1] + b2r, 0.f) * w3r;
                float s2 = fmaxf(acc[2] + b2r, 0.f) * w3r;
                float s3 = fmaxf(acc[3] + b2r, 0.f) * w3r;
                #pragma unroll
                for (int off = 1; off < 16; off <<= 1) {
                    s0 += __shfl_xor(s0, off);
                    s1 += __shfl_xor(s1, off);
                    s2 += __shfl_xor(s2, off);
                    s3 += __shfl_xor(s3, off);
                }
                if (lr == 0) {
                    f32x4 sv = {s0, s1, s2, s3};
                    *reinterpret_cast<f32x4*>(
                        &logits[i][jb0 + u * 16 + lg * 4]) = sv;
                }
            }
        }
    }
    __syncthreads();

    // ---- softmax: wave (si, half) owns 256 keys of query si ----
    const int si = w >> 1, hf = w & 1;
    const int qi = i0 + si;
    const int j0 = hf * 256 + lane * 4;
    const f32x4 raw = *reinterpret_cast<const f32x4*>(&logits[si][j0]);
    const size_t po = ((size_t)(g * SQ + qi)) * SQ + j0;
    const f32x4 pm4 = *reinterpret_cast<const f32x4*>(pos_mul + po);
    const f32x4 pa4 = *reinterpret_cast<const f32x4*>(pos_add + po);
    f32x4 lgt;
    #pragma unroll
    for (int c = 0; c < 4; ++c)
        lgt[c] = fmaf(fmaxf(raw[c] + b3s, 0.f), pm4[c], pa4[c]);
    float m = fmaxf(fmaxf(lgt[0], lgt[1]), fmaxf(lgt[2], lgt[3]));
    #pragma unroll
    for (int off = 1; off < 64; off <<= 1) m = fmaxf(m, __shfl_xor(m, off));
    if (lane == 0) redm[si][hf] = m;
    __syncthreads();
    const float M = fmaxf(redm[si][0], redm[si][1]);
    f32x4 e4;
    float ls = 0.f;
    #pragma unroll
    for (int c = 0; c < 4; ++c) { e4[c] = __expf(lgt[c] - M); ls += e4[c]; }
    #pragma unroll
    for (int c = 0; c < 4; ++c) pbuf[(j0 + c) * 4 + si] = e4[c];
    #pragma unroll
    for (int off = 1; off < 64; off <<= 1) ls += __shfl_xor(ls, off);
    if (lane == 0) reds[si][hf] = ls;
    __syncthreads();

    // ---- A@V: wave w handles keyblock w; lane = output dim; 4 queries ----
    f32x4 av = {0.f, 0.f, 0.f, 0.f};
    const float* vb =
        Vp + (((size_t)(b * SQ + w * 64)) * NGQ + g) * DGQ + lane;
    #pragma unroll 8
    for (int n = 0; n < 64; ++n) {
        const float v = vb[(size_t)n * (NGQ * DGQ)];        // coalesced, L2
        const f32x4 p4 =
            *reinterpret_cast<const f32x4*>(&pbuf[(w * 64 + n) * 4]); // bcast
        av += v * p4;                                       // v_pk_fma x2
    }
    *reinterpret_cast<f32x4*>(&avs[w][lane][0]) = av;
    __syncthreads();

    if (t < 256) {
        const int i2 = t >> 6, d = t & 63;
        float sum = 0.f;
        #pragma unroll
        for (int ww = 0; ww < 8; ++ww) sum += avs[ww][d][i2];
        const float den = reds[i2][0] + reds[i2][1];
        out[((size_t)(b * SQ + i0 + i2)) * DQ + d * NGQ + g] = sum / den;
    }
}

extern "C" void kernel_launch(void* const* d_in, const int* in_sizes, int n_in,
                              void* d_out, int out_size, void* d_ws, size_t ws_size,
                              hipStream_t stream) {
    const float* x       = (const float*)d_in[0];
    const float* pos_add = (const float*)d_in[1];
    const float* pos_mul = (const float*)d_in[2];
    const float* Wq      = (const float*)d_in[3];
    const float* Wk      = (const float*)d_in[4];
    const float* Wv      = (const float*)d_in[5];
    const float* W1      = (const float*)d_in[6];
    const float* b1      = (const float*)d_in[7];
    const float* W2      = (const float*)d_in[8];
    const float* b2      = (const float*)d_in[9];
    const float* W3      = (const float*)d_in[10];
    const float* b3      = (const float*)d_in[11];
    float* out = (float*)d_out;

    float* ws  = (float*)d_ws;
    float* QW1 = ws;
    float* KW1 = ws + 131072;
    float* Vp  = ws + 262144;

    proj_kernel<<<BQ * SQ, 256, 0, stream>>>(x, Wq, Wk, Wv, W1, b1,
                                             QW1, KW1, Vp);
    attn_kernel<<<BQ * NGQ * SQ / 4, 512, 0, stream>>>(QW1, KW1, Vp, W2, b2,
                                                       W3, b3, pos_add, pos_mul,
                                                       out);
}